// Round 5
// baseline (254.802 us; speedup 1.0000x reference)
//
#include <hip/hip_runtime.h>

typedef float fx4 __attribute__((ext_vector_type(4)));   // native vec type for nontemporal builtin

__device__ __forceinline__ void nt_store4(float4* p, float4 v) {
    fx4 vv = {v.x, v.y, v.z, v.w};
    __builtin_nontemporal_store(vv, (fx4*)p);
}

// Quad permute via DPP (VALU, no LDS/DS, no lgkmcnt): out[lane] = in[quad[lane&3]]
template<int CTRL>
__device__ __forceinline__ float qperm(float v) {
    return __int_as_float(__builtin_amdgcn_update_dpp(
        0, __float_as_int(v), CTRL, 0xF, 0xF, true));
}
template<int CTRL>
__device__ __forceinline__ float4 qperm4(float4 v) {
    float4 r;
    r.x = qperm<CTRL>(v.x);
    r.y = qperm<CTRL>(v.y);
    r.z = qperm<CTRL>(v.z);
    r.w = qperm<CTRL>(v.w);
    return r;
}

// quad_perm ctrl byte: [1:0]=src for lane0, [3:2]=lane1, [5:4]=lane2, [7:6]=lane3
#define ROT1 0xC9   // [1,2,0,3]: lane r<3 reads lane (r+1)%3
#define ROT2 0xD2   // [2,0,1,3]: lane r<3 reads lane (r+2)%3
#define BC3  0xFF   // broadcast lane 3

// Rodrigues in cyclic form, one output row per lane (4 lanes per pose).
// row r of R: diag -> col r, off1 -> col (r+1)%3, off2 -> col (r+2)%3
__device__ __forceinline__ float4 compose_row(
    float2 f0, float2 f1, float2 f2_,   // (t0,t1),(t2,w0),(w1,w2)
    float4 pr, int r)
{
    float t0 = f0.x, t1 = f0.y, t2 = f1.x;
    float w0 = f1.y, w1 = f2_.x, w2 = f2_.y;

    // A = sin(t)/t, B = (1-cos(t))/t^2, series in x = t^2
    float x = w0 * w0 + w1 * w1 + w2 * w2;
    float A, B;
    if (__builtin_expect(x < 2.25f, 1)) {
        // |err| < ~1.5e-6 for theta < 1.5; series limit == reference small-angle branch
        A = 1.0f + x * (-1.0f / 6.0f  + x * (1.0f / 120.0f + x * (-1.0f / 5040.0f  + x * (1.0f / 362880.0f))));
        B = 0.5f + x * (-1.0f / 24.0f + x * (1.0f / 720.0f + x * (-1.0f / 40320.0f + x * (1.0f / 3628800.0f))));
    } else {
        // exact fallback (never taken for this distribution; keeps kernel general)
        float th = sqrtf(x);
        A = sinf(th) / th;
        B = (1.0f - cosf(th)) / x;
    }

    float wr = (r == 0) ? w0 : (r == 1) ? w1 : w2;
    float tr = (r == 0) ? t0 : (r == 1) ? t1 : (r == 2) ? t2 : 0.0f;

    float wa = qperm<ROT1>(wr);   // w[(r+1)%3]
    float wb = qperm<ROT2>(wr);   // w[(r+2)%3]

    float4 Pa = qperm4<ROT1>(pr); // pose row (r+1)%3
    float4 Pb = qperm4<ROT2>(pr); // pose row (r+2)%3
    float4 P3 = qperm4<BC3>(pr);  // pose row 3

    float diag = 1.0f - B * (wa * wa + wb * wb);
    float off1 = B * wr * wa - A * wb;
    float off2 = B * wr * wb + A * wa;
    if (r == 3) { diag = 1.0f; off1 = 0.0f; off2 = 0.0f; }  // T row3 = [0,0,0,1]

    float4 o;
    o.x = diag * pr.x + off1 * Pa.x + off2 * Pb.x + tr * P3.x;
    o.y = diag * pr.y + off1 * Pa.y + off2 * Pb.y + tr * P3.y;
    o.z = diag * pr.z + off1 * Pa.z + off2 * Pb.z + tr * P3.z;
    o.w = diag * pr.w + off1 * Pa.w + off2 * Pb.w + tr * P3.w;
    return o;
}

// Persistent-wave grid-stride with a 2-deep software pipeline:
// each iteration issues NEXT pose's loads before computing the CURRENT pose,
// so every resident wave keeps a full load set in flight at all times.
// Grid capped at 2048 workgroups (8 blocks/CU) -> no block churn.
// stride is a multiple of 4, so the lane's quad role r is loop-invariant.
__global__ __launch_bounds__(256) void se3_compose_kernel(
    const float* __restrict__ xi,
    const float4* __restrict__ poses4,   // flat float4 view, length 4*n
    float4* __restrict__ out4,           // flat float4 view, length 4*n
    int n4)                              // = 4*n
{
    int tid    = blockIdx.x * blockDim.x + threadIdx.x;
    int stride = gridDim.x * blockDim.x;   // multiple of 4
    if (tid >= n4) return;

    int r = tid & 3;   // loop-invariant quad role

    // ---- prologue: load iteration 0 ----
    int i = tid;
    float4 pr = poses4[i];
    const float2* x2 = (const float2*)(xi + 6ll * (i >> 2));
    float2 f0 = x2[0], f1 = x2[1], f2_ = x2[2];

    int inext = i + stride;
    while (inext < n4) {
        // ---- issue next iteration's loads (independent of current compute) ----
        float4 prN = poses4[inext];
        const float2* x2N = (const float2*)(xi + 6ll * (inext >> 2));
        float2 f0N = x2N[0], f1N = x2N[1], f2N = x2N[2];

        // ---- compute + store current (overlaps with the loads above) ----
        float4 o = compose_row(f0, f1, f2_, pr, r);
        nt_store4(&out4[i], o);

        // ---- rotate pipeline ----
        i = inext; inext += stride;
        pr = prN; f0 = f0N; f1 = f1N; f2_ = f2N;
    }

    // ---- epilogue ----
    float4 o = compose_row(f0, f1, f2_, pr, r);
    nt_store4(&out4[i], o);
}

extern "C" void kernel_launch(void* const* d_in, const int* in_sizes, int n_in,
                              void* d_out, int out_size, void* d_ws, size_t ws_size,
                              hipStream_t stream) {
    const float*  xi     = (const float*)d_in[0];
    const float4* poses4 = (const float4*)d_in[1];
    float4*       out4   = (float4*)d_out;

    int n  = in_sizes[0] / 6;  // N = 2,000,000
    int n4 = 4 * n;

    const int block = 256;
    int grid = (n4 + block - 1) / block;
    if (grid > 2048) grid = 2048;          // 8 workgroups/CU * 256 CUs: persistent waves
    se3_compose_kernel<<<grid, block, 0, stream>>>(xi, poses4, out4, n4);
}

// Round 6
// 235.149 us; speedup vs baseline: 1.0836x; 1.0836x over previous
//
#include <hip/hip_runtime.h>

typedef float fx4 __attribute__((ext_vector_type(4)));   // native vec types for nontemporal builtins
typedef float fx2 __attribute__((ext_vector_type(2)));

__device__ __forceinline__ void nt_store4(float4* p, float4 v) {
    fx4 vv = {v.x, v.y, v.z, v.w};
    __builtin_nontemporal_store(vv, (fx4*)p);
}
__device__ __forceinline__ float4 nt_load4(const float4* p) {
    fx4 vv = __builtin_nontemporal_load((const fx4*)p);
    float4 r; r.x = vv.x; r.y = vv.y; r.z = vv.z; r.w = vv.w;
    return r;
}
__device__ __forceinline__ float2 nt_load2(const float2* p) {
    fx2 vv = __builtin_nontemporal_load((const fx2*)p);
    float2 r; r.x = vv.x; r.y = vv.y;
    return r;
}

// Quad permute via DPP (VALU, no LDS/DS, no lgkmcnt): out[lane] = in[quad[lane&3]]
template<int CTRL>
__device__ __forceinline__ float qperm(float v) {
    return __int_as_float(__builtin_amdgcn_update_dpp(
        0, __float_as_int(v), CTRL, 0xF, 0xF, true));
}
template<int CTRL>
__device__ __forceinline__ float4 qperm4(float4 v) {
    float4 r;
    r.x = qperm<CTRL>(v.x);
    r.y = qperm<CTRL>(v.y);
    r.z = qperm<CTRL>(v.z);
    r.w = qperm<CTRL>(v.w);
    return r;
}

// quad_perm ctrl byte: [1:0]=src for lane0, [3:2]=lane1, [5:4]=lane2, [7:6]=lane3
#define ROT1 0xC9   // [1,2,0,3]: lane r<3 reads lane (r+1)%3
#define ROT2 0xD2   // [2,0,1,3]: lane r<3 reads lane (r+2)%3
#define BC3  0xFF   // broadcast lane 3

// 4 lanes per pose: lane j -> pose p=j>>2, row r=j&3. All global access coalesced 16B/lane.
// Rodrigues cyclic form: row r of R = [diag -> col r, off1 -> col (r+1)%3, off2 -> col (r+2)%3]
// ALL loads nontemporal: data is pure streaming (no cross-wave reuse) -> bypass L1
// allocation so the per-CU miss path isn't the concurrency cap (T-L1 experiment).
__global__ __launch_bounds__(256) void se3_compose_kernel(
    const float* __restrict__ xi,
    const float4* __restrict__ poses4,   // flat float4 view, length 4*n
    float4* __restrict__ out4,           // flat float4 view, length 4*n
    int n4)                              // = 4*n
{
    int i = blockIdx.x * blockDim.x + threadIdx.x;
    if (i >= n4) return;

    int p = i >> 2;   // pose index
    int r = i & 3;    // my row

    // ---- xi[p, 0:6] (quad-redundant; same-line requests coalesce in-instruction) ----
    const float2* x2 = (const float2*)(xi + 6ll * p);
    float2 a  = nt_load2(x2 + 0);   // t0 t1
    float2 b  = nt_load2(x2 + 1);   // t2 w0
    float2 cc = nt_load2(x2 + 2);   // w1 w2
    float t0 = a.x, t1 = a.y, t2 = b.x;
    float w0 = b.y, w1 = cc.x, w2 = cc.y;

    // ---- my pose row: perfectly coalesced float4 ----
    float4 pr = nt_load4(&poses4[i]);

    // ---- A = sin(t)/t, B = (1-cos(t))/t^2, series in x = t^2 ----
    float x = w0 * w0 + w1 * w1 + w2 * w2;
    float A, B;
    if (__builtin_expect(x < 2.25f, 1)) {
        // |err| < ~1.5e-6 for theta < 1.5; series limit == reference small-angle branch
        A = 1.0f + x * (-1.0f / 6.0f  + x * (1.0f / 120.0f + x * (-1.0f / 5040.0f  + x * (1.0f / 362880.0f))));
        B = 0.5f + x * (-1.0f / 24.0f + x * (1.0f / 720.0f + x * (-1.0f / 40320.0f + x * (1.0f / 3628800.0f))));
    } else {
        // exact fallback (never taken for this distribution; keeps kernel general)
        float th = sqrtf(x);
        A = sinf(th) / th;
        B = (1.0f - cosf(th)) / x;
    }

    // ---- per-row values ----
    float wr = (r == 0) ? w0 : (r == 1) ? w1 : w2;
    float tr = (r == 0) ? t0 : (r == 1) ? t1 : (r == 2) ? t2 : 0.0f;

    float wa = qperm<ROT1>(wr);   // w[(r+1)%3]
    float wb = qperm<ROT2>(wr);   // w[(r+2)%3]

    float4 Pa = qperm4<ROT1>(pr); // pose row (r+1)%3
    float4 Pb = qperm4<ROT2>(pr); // pose row (r+2)%3
    float4 P3 = qperm4<BC3>(pr);  // pose row 3

    float diag = 1.0f - B * (wa * wa + wb * wb);
    float off1 = B * wr * wa - A * wb;
    float off2 = B * wr * wb + A * wa;
    if (r == 3) { diag = 1.0f; off1 = 0.0f; off2 = 0.0f; }  // T row3 = [0,0,0,1]

    float4 o;
    o.x = diag * pr.x + off1 * Pa.x + off2 * Pb.x + tr * P3.x;
    o.y = diag * pr.y + off1 * Pa.y + off2 * Pb.y + tr * P3.y;
    o.z = diag * pr.z + off1 * Pa.z + off2 * Pb.z + tr * P3.z;
    o.w = diag * pr.w + off1 * Pa.w + off2 * Pb.w + tr * P3.w;

    nt_store4(&out4[i], o);   // coalesced: wave writes 1KB contiguous
}

extern "C" void kernel_launch(void* const* d_in, const int* in_sizes, int n_in,
                              void* d_out, int out_size, void* d_ws, size_t ws_size,
                              hipStream_t stream) {
    const float*  xi     = (const float*)d_in[0];
    const float4* poses4 = (const float4*)d_in[1];
    float4*       out4   = (float4*)d_out;

    int n  = in_sizes[0] / 6;  // N = 2,000,000
    int n4 = 4 * n;

    const int block = 256;
    const int grid  = (n4 + block - 1) / block;
    se3_compose_kernel<<<grid, block, 0, stream>>>(xi, poses4, out4, n4);
}